// Round 7
// baseline (638.889 us; speedup 1.0000x reference)
//
#include <hip/hip_runtime.h>
#include <cmath>

#define B_   8
#define CI_  3
#define CM_  21
#define H_   128
#define W_   128
#define K_   32
#define PAD_ 8
#define PW_  144
#define PH_  144
#define NC_  7   // mask channels per block in iter kernel (21 = 3 groups of 7)

typedef float f4 __attribute__((ext_vector_type(4)));
typedef _Float16 h4 __attribute__((ext_vector_type(4)));

struct PosSoft { float v[K_]; };

// shifted window: elements [S .. S+3] of concat(A,B); pure register selection.
template<int S>
__device__ __forceinline__ f4 shw(f4 A, f4 B) {
  if constexpr (S == 0) return A;
  else if constexpr (S == 1) return (f4){A.y, A.z, A.w, B.x};
  else if constexpr (S == 2) return (f4){A.z, A.w, B.x, B.y};
  else                       return (f4){A.w, B.x, B.y, B.z};
}

// aligned h4 load (8 B, full-line coalesced) + widen to f4
__device__ __forceinline__ f4 ldh(const _Float16* p, int off) {
  return __builtin_convertvector(*reinterpret_cast<const h4*>(p + off), f4);
}

// ---------------------------------------------------------------------------
// Phase A: per-pixel affinity (softmax over K=32) + constant position term.
// Output layout: aff[b][i][k][j]  (k-major per row, j contiguous), fp16.
// ---------------------------------------------------------------------------
__global__ __launch_bounds__(128) void aff_kernel(const float* __restrict__ imgs,
                                                  _Float16* __restrict__ aff,
                                                  PosSoft ps) {
  constexpr int OI[8] = {-1,-1,-1, 0, 0, 1, 1, 1};
  constexpr int OJ[8] = {-1, 0, 1,-1, 1,-1, 0, 1};
  const int j = threadIdx.x;
  const int i = blockIdx.x;
  const int b = blockIdx.y;
  const float* img = imgs + (size_t)b * CI_ * H_ * W_;

  float ctr[CI_];
#pragma unroll
  for (int c = 0; c < CI_; ++c) ctr[c] = img[c * H_ * W_ + i * W_ + j];

  float s[CI_] = {0.f, 0.f, 0.f}, s2[CI_] = {0.f, 0.f, 0.f};
#pragma unroll
  for (int k = 0; k < K_; ++k) {
    const int d  = 1 << (k >> 3);
    const int ci = min(max(i + OI[k & 7] * d, 0), H_ - 1);
    const int cj = min(max(j + OJ[k & 7] * d, 0), W_ - 1);
#pragma unroll
    for (int c = 0; c < CI_; ++c) {
      float v = img[c * H_ * W_ + ci * W_ + cj];
      s[c] += v; s2[c] += v * v;
    }
  }

  float inv[CI_];
#pragma unroll
  for (int c = 0; c < CI_; ++c) {
    float mean = s[c] * (1.f / K_);
    float var  = (s2[c] - (float)K_ * mean * mean) * (1.f / (K_ - 1));
    var = fmaxf(var, 0.f);
    inv[c] = 1.f / ((sqrtf(var) + 1e-8f) * 0.3f);
  }

  float araw[K_];
#pragma unroll
  for (int k = 0; k < K_; ++k) {
    const int d  = 1 << (k >> 3);
    const int ci = min(max(i + OI[k & 7] * d, 0), H_ - 1);
    const int cj = min(max(j + OJ[k & 7] * d, 0), W_ - 1);
    float t = 0.f;
#pragma unroll
    for (int c = 0; c < CI_; ++c) {
      float v  = img[c * H_ * W_ + ci * W_ + cj];
      float dd = fabsf(v - ctr[c]) * inv[c];
      t += dd * dd;
    }
    araw[k] = -t * (1.f / CI_);
  }

  float m = araw[0];
#pragma unroll
  for (int k = 1; k < K_; ++k) m = fmaxf(m, araw[k]);
  float sum = 0.f;
#pragma unroll
  for (int k = 0; k < K_; ++k) { float e = __expf(araw[k] - m); araw[k] = e; sum += e; }
  const float rs = 1.f / sum;

  _Float16* ap = aff + ((size_t)(b * H_ + i) * K_) * W_ + j;
#pragma unroll
  for (int k = 0; k < K_; ++k) ap[k * W_] = (_Float16)(araw[k] * rs + ps.v[k]);
}

// ---------------------------------------------------------------------------
// Pad masks into edge-replicated 144x144 fp16 planes. One h4 slot per thread.
// ---------------------------------------------------------------------------
__global__ void pad_kernel(const float* __restrict__ src, _Float16* __restrict__ dst,
                           int total4) {
  int idx = blockIdx.x * blockDim.x + threadIdx.x;
  if (idx >= total4) return;
  int q  = idx % (PW_ / 4);
  int t  = idx / (PW_ / 4);
  int pi = t % PH_;
  int p  = t / PH_;
  int i = min(max(pi - PAD_, 0), H_ - 1);
  const float* srow = src + (size_t)p * (H_ * W_) + i * W_;
  h4 o;
#pragma unroll
  for (int e = 0; e < 4; ++e) {
    int j = min(max(q * 4 + e - PAD_, 0), W_ - 1);
    o[e] = (_Float16)srow[j];
  }
  *reinterpret_cast<h4*>(dst + (size_t)p * (PH_ * PW_) + pi * PW_ + q * 4) = o;
}

// ---------------------------------------------------------------------------
// iter_kernel tap macros. Thread owns 4 px of one row, 7 channels. qNm = (row
// i-4, col j0) of channel N; qNp = (row i+4, col j0). Offsets in HALF units.
// All compile-time immediates; all locals named scalars (nothing address-
// taken, nothing runtime-indexed).
// ---------------------------------------------------------------------------

// horizontal taps, all 4 dilations, one channel (center row = PM + 4*PW_)
#define HCH(PM, ACC) do {                                                      \
    f4 m2 = ldh(PM, 4 * PW_ - 8), m1 = ldh(PM, 4 * PW_ - 4);                   \
    f4 c0 = ldh(PM, 4 * PW_),     c1 = ldh(PM, 4 * PW_ + 4);                   \
    f4 c2 = ldh(PM, 4 * PW_ + 8);                                              \
    ACC += h1m * shw<3>(m1, c0) + h1p * shw<1>(c0, c1);                        \
    ACC += h2m * shw<2>(m1, c0) + h2p * shw<2>(c0, c1);                        \
    ACC += h4m * m1 + h4p * c1;                                                \
    ACC += h8m * m2 + h8p * c2;                                                \
  } while (0)

// vertical+diagonal taps, shifted dilation D in {1,2}, SM = 4-D
#define VCHS(D, SM, PM, PP, ACC) do {                                          \
    f4 ua = ldh(PM, (4 - D) * PW_ - 4), ub = ldh(PM, (4 - D) * PW_);           \
    f4 uc = ldh(PM, (4 - D) * PW_ + 4);                                        \
    ACC += A0 * shw<SM>(ua, ub) + A1 * ub + A2 * shw<D>(ub, uc);               \
    f4 da = ldh(PP, (D - 4) * PW_ - 4), db = ldh(PP, (D - 4) * PW_);           \
    f4 dc = ldh(PP, (D - 4) * PW_ + 4);                                        \
    ACC += A5 * shw<SM>(da, db) + A6 * db + A7 * shw<D>(db, dc);               \
  } while (0)

// vertical+diagonal taps, aligned dilation 4
#define VCH4(PM, PP, ACC) do {                                                 \
    f4 ua = ldh(PM, -4), ub = ldh(PM, 0), uc = ldh(PM, 4);                     \
    ACC += A0 * ua + A1 * ub + A2 * uc;                                        \
    f4 da = ldh(PP, -4), db = ldh(PP, 0), dc = ldh(PP, 4);                     \
    ACC += A5 * da + A6 * db + A7 * dc;                                        \
  } while (0)

// vertical+diagonal taps, aligned dilation 8 (rows i-8 / i+8)
#define VCH8(PM, PP, ACC) do {                                                 \
    f4 ua = ldh(PM, -4 * PW_ - 8), ub = ldh(PM, -4 * PW_);                     \
    f4 uc = ldh(PM, -4 * PW_ + 8);                                             \
    ACC += A0 * ua + A1 * ub + A2 * uc;                                        \
    f4 da = ldh(PP, 4 * PW_ - 8), db = ldh(PP, 4 * PW_);                       \
    f4 dc = ldh(PP, 4 * PW_ + 8);                                              \
    ACC += A5 * da + A6 * db + A7 * dc;                                        \
  } while (0)

// per-dilation vertical aff fragment loads (6 f4 regs, fp16 source)
#define AFFV(AB)                                                               \
    f4 A0 = ldh(AB, 0),      A1 = ldh(AB, W_),     A2 = ldh(AB, 2 * W_);       \
    f4 A5 = ldh(AB, 5 * W_), A6 = ldh(AB, 6 * W_), A7 = ldh(AB, 7 * W_);

#define VALL(MAC, ...) \
    MAC(__VA_ARGS__ q0m, q0p, acc0); MAC(__VA_ARGS__ q1m, q1p, acc1);          \
    MAC(__VA_ARGS__ q2m, q2p, acc2); MAC(__VA_ARGS__ q3m, q3p, acc3);          \
    MAC(__VA_ARGS__ q4m, q4p, acc4); MAC(__VA_ARGS__ q5m, q5p, acc5);          \
    MAC(__VA_ARGS__ q6m, q6p, acc6);

// ---------------------------------------------------------------------------
// Propagation step. Block 64 thr = 2 rows x 32 col-quads (4 px/thread),
// 7 channels. Grid 1536, XCD-pinned: b = bid & 7. fp16 planes + fp16 aff,
// f32 accumulation. PADOUT=1 -> fp16 padded dst; PADOUT=0 -> f32 d_out.
// ---------------------------------------------------------------------------
template <int PADOUT>
__global__ __launch_bounds__(64, 2) void iter_kernel(const _Float16* __restrict__ src,
                                                     const _Float16* __restrict__ aff,
                                                     void* __restrict__ dstv) {
  const int bid  = blockIdx.x;
  const int b    = bid & 7;
  const int t    = bid >> 3;
  const int grp  = t % 3;
  const int tile = t / 3;            // 0..63

  const int tid = threadIdx.x;
  const int qx  = tid & 31;
  const int j0  = qx * 4;
  const int i   = tile * 2 + (tid >> 5);
  const int c0  = grp * NC_;

  constexpr int CHP = PH_ * PW_;
  const _Float16* base = src + (size_t)(b * CM_ + c0) * CHP + (i + PAD_) * PW_ + (j0 + PAD_);
  const _Float16* q0m = base           - 4 * PW_;  const _Float16* q0p = base           + 4 * PW_;
  const _Float16* q1m = q0m +     CHP;             const _Float16* q1p = q0p +     CHP;
  const _Float16* q2m = q0m + 2 * CHP;             const _Float16* q2p = q0p + 2 * CHP;
  const _Float16* q3m = q0m + 3 * CHP;             const _Float16* q3p = q0p + 3 * CHP;
  const _Float16* q4m = q0m + 4 * CHP;             const _Float16* q4p = q0p + 4 * CHP;
  const _Float16* q5m = q0m + 5 * CHP;             const _Float16* q5p = q0p + 5 * CHP;
  const _Float16* q6m = q0m + 6 * CHP;             const _Float16* q6p = q0p + 6 * CHP;

  const _Float16* ab0 = aff + ((size_t)(b * H_ + i) * K_) * W_ + j0;
  const _Float16* ab1 = ab0 +  8 * W_;
  const _Float16* ab2 = ab0 + 16 * W_;
  const _Float16* ab3 = ab0 + 24 * W_;

  f4 acc0 = (f4){0.f,0.f,0.f,0.f}, acc1 = (f4){0.f,0.f,0.f,0.f};
  f4 acc2 = (f4){0.f,0.f,0.f,0.f}, acc3 = (f4){0.f,0.f,0.f,0.f};
  f4 acc4 = (f4){0.f,0.f,0.f,0.f}, acc5 = (f4){0.f,0.f,0.f,0.f};
  f4 acc6 = (f4){0.f,0.f,0.f,0.f};

  // ---- horizontal pass: 8 aff regs + 5 center-row loads per channel
  {
    f4 h1m = ldh(ab0, 3 * W_), h1p = ldh(ab0, 4 * W_);
    f4 h2m = ldh(ab1, 3 * W_), h2p = ldh(ab1, 4 * W_);
    f4 h4m = ldh(ab2, 3 * W_), h4p = ldh(ab2, 4 * W_);
    f4 h8m = ldh(ab3, 3 * W_), h8p = ldh(ab3, 4 * W_);
    HCH(q0m, acc0); HCH(q1m, acc1); HCH(q2m, acc2); HCH(q3m, acc3);
    HCH(q4m, acc4); HCH(q5m, acc5); HCH(q6m, acc6);
  }
  // ---- vertical/diagonal passes, one dilation at a time
  { AFFV(ab0); VALL(VCHS, 1, 3,) }
  { AFFV(ab1); VALL(VCHS, 2, 2,) }
  { AFFV(ab2); VALL(VCH4,) }
  { AFFV(ab3); VALL(VCH8,) }

  // ---- epilogue
  if (PADOUT) {
    const int pr = i + PAD_;
    const int r0 = (i == 0)      ? 0         : pr;
    const int r1 = (i == H_ - 1) ? (PH_ - 1) : pr;
#define EPI_CH(ACC, CIDX) do {                                                 \
      _Float16* dch = (_Float16*)dstv + (size_t)(b * CM_ + c0 + CIDX) * CHP;   \
      h4 o = __builtin_convertvector(ACC, h4);                                 \
      for (int r = r0; r <= r1; ++r) {                                         \
        _Float16* row = dch + r * PW_;                                         \
        *reinterpret_cast<h4*>(row + PAD_ + j0) = o;                           \
        if (qx == 0) { h4 sp = (h4){o.x, o.x, o.x, o.x};                       \
          *reinterpret_cast<h4*>(row) = sp;                                    \
          *reinterpret_cast<h4*>(row + 4) = sp; }                              \
        if (qx == 31) { h4 sp = (h4){o.w, o.w, o.w, o.w};                      \
          *reinterpret_cast<h4*>(row + PW_ - 8) = sp;                          \
          *reinterpret_cast<h4*>(row + PW_ - 4) = sp; }                        \
      }                                                                        \
    } while (0)
    EPI_CH(acc0, 0); EPI_CH(acc1, 1); EPI_CH(acc2, 2); EPI_CH(acc3, 3);
    EPI_CH(acc4, 4); EPI_CH(acc5, 5); EPI_CH(acc6, 6);
#undef EPI_CH
  } else {
    float* dc = (float*)dstv + (size_t)(b * CM_ + c0) * (H_ * W_) + (size_t)i * W_ + j0;
    *reinterpret_cast<f4*>(dc)                 = acc0;
    *reinterpret_cast<f4*>(dc + 1 * (H_ * W_)) = acc1;
    *reinterpret_cast<f4*>(dc + 2 * (H_ * W_)) = acc2;
    *reinterpret_cast<f4*>(dc + 3 * (H_ * W_)) = acc3;
    *reinterpret_cast<f4*>(dc + 4 * (H_ * W_)) = acc4;
    *reinterpret_cast<f4*>(dc + 5 * (H_ * W_)) = acc5;
    *reinterpret_cast<f4*>(dc + 6 * (H_ * W_)) = acc6;
  }
}

// ---------------------------------------------------------------------------
extern "C" void kernel_launch(void* const* d_in, const int* in_sizes, int n_in,
                              void* d_out, int out_size, void* d_ws, size_t ws_size,
                              hipStream_t stream) {
  const float* imgs  = (const float*)d_in[0];
  const float* masks = (const float*)d_in[1];
  float* out = (float*)d_out;

  char* ws = (char*)d_ws;
  const size_t affBytes = (size_t)B_ * K_ * H_ * W_ * sizeof(_Float16);     // 8.4 MB
  const size_t padBytes = (size_t)B_ * CM_ * PH_ * PW_ * sizeof(_Float16);  // 7.0 MB
  _Float16* aff = (_Float16*)ws;
  _Float16* P0  = (_Float16*)(ws + affBytes);
  _Float16* P1  = (_Float16*)(ws + affBytes + padBytes);

  PosSoft ps;
  {
    const double pv[8] = {1.4142135623730951, 1.0, 1.4142135623730951, 1.0,
                          1.0, 1.4142135623730951, 1.0, 1.4142135623730951};
    double pos[K_];
    for (int di = 0; di < 4; ++di) {
      double d = (double)(1 << di);
      for (int o = 0; o < 8; ++o) pos[di * 8 + o] = pv[o] * d;
    }
    double mean = 0; for (int k = 0; k < K_; ++k) mean += pos[k]; mean /= K_;
    double var = 0;  for (int k = 0; k < K_; ++k) { double dd = pos[k] - mean; var += dd * dd; }
    var /= (K_ - 1);
    double sd = sqrt(var);
    double pa[K_]; double m = -1e300;
    for (int k = 0; k < K_; ++k) {
      double r = pos[k] / ((sd + 1e-8) * 0.3);
      pa[k] = -(r * r);
      if (pa[k] > m) m = pa[k];
    }
    double es = 0; for (int k = 0; k < K_; ++k) { pa[k] = exp(pa[k] - m); es += pa[k]; }
    for (int k = 0; k < K_; ++k) ps.v[k] = (float)(0.01 * pa[k] / es);
  }

  aff_kernel<<<dim3(H_, B_), 128, 0, stream>>>(imgs, aff, ps);

  const int total4 = B_ * CM_ * PH_ * (PW_ / 4);
  pad_kernel<<<(total4 + 255) / 256, 256, 0, stream>>>(masks, P0, total4);

  const int nblk = B_ * 3 * (H_ / 2);   // 1536, XCD-pinned decode in kernel
  _Float16* s = P0;
  _Float16* d = P1;
  for (int it = 0; it < 9; ++it) {
    iter_kernel<1><<<nblk, 64, 0, stream>>>(s, aff, (void*)d);
    _Float16* tm = s; s = d; d = tm;
  }
  iter_kernel<0><<<nblk, 64, 0, stream>>>(s, aff, (void*)out);
}

// Round 8
// 205.336 us; speedup vs baseline: 3.1114x; 3.1114x over previous
//
#include <hip/hip_runtime.h>
#include <cmath>

#define B_   8
#define CI_  3
#define CM_  21
#define H_   128
#define W_   128
#define K_   32
#define PAD_ 8
#define PW_  144
#define PH_  144
#define NC_  3   // mask channels per block in iter kernel (21 = 7 groups of 3)

typedef float f4 __attribute__((ext_vector_type(4)));
typedef _Float16 h4 __attribute__((ext_vector_type(4)));

struct PosSoft { float v[K_]; };

// shifted window: elements [S .. S+3] of concat(A,B); pure register selection.
template<int S>
__device__ __forceinline__ f4 shw(f4 A, f4 B) {
  if constexpr (S == 0) return A;
  else if constexpr (S == 1) return (f4){A.y, A.z, A.w, B.x};
  else if constexpr (S == 2) return (f4){A.z, A.w, B.x, B.y};
  else                       return (f4){A.w, B.x, B.y, B.z};
}

// aligned h4 load (8 B, full-line coalesced) + widen to f4  [cached: masks]
__device__ __forceinline__ f4 ldh(const _Float16* p, int off) {
  return __builtin_convertvector(*reinterpret_cast<const h4*>(p + off), f4);
}
// non-temporal h4 load + widen  [streaming: aff, zero intra-block reuse]
__device__ __forceinline__ f4 ldh_nt(const _Float16* p, int off) {
  return __builtin_convertvector(
      __builtin_nontemporal_load(reinterpret_cast<const h4*>(p + off)), f4);
}

// ---------------------------------------------------------------------------
// Phase A: per-pixel affinity (softmax over K=32) + constant position term.
// Output layout: aff[b][i][k][j]  (k-major per row, j contiguous), fp16.
// ---------------------------------------------------------------------------
__global__ __launch_bounds__(128) void aff_kernel(const float* __restrict__ imgs,
                                                  _Float16* __restrict__ aff,
                                                  PosSoft ps) {
  constexpr int OI[8] = {-1,-1,-1, 0, 0, 1, 1, 1};
  constexpr int OJ[8] = {-1, 0, 1,-1, 1,-1, 0, 1};
  const int j = threadIdx.x;
  const int i = blockIdx.x;
  const int b = blockIdx.y;
  const float* img = imgs + (size_t)b * CI_ * H_ * W_;

  float ctr[CI_];
#pragma unroll
  for (int c = 0; c < CI_; ++c) ctr[c] = img[c * H_ * W_ + i * W_ + j];

  float s[CI_] = {0.f, 0.f, 0.f}, s2[CI_] = {0.f, 0.f, 0.f};
#pragma unroll
  for (int k = 0; k < K_; ++k) {
    const int d  = 1 << (k >> 3);
    const int ci = min(max(i + OI[k & 7] * d, 0), H_ - 1);
    const int cj = min(max(j + OJ[k & 7] * d, 0), W_ - 1);
#pragma unroll
    for (int c = 0; c < CI_; ++c) {
      float v = img[c * H_ * W_ + ci * W_ + cj];
      s[c] += v; s2[c] += v * v;
    }
  }

  float inv[CI_];
#pragma unroll
  for (int c = 0; c < CI_; ++c) {
    float mean = s[c] * (1.f / K_);
    float var  = (s2[c] - (float)K_ * mean * mean) * (1.f / (K_ - 1));
    var = fmaxf(var, 0.f);
    inv[c] = 1.f / ((sqrtf(var) + 1e-8f) * 0.3f);
  }

  float araw[K_];
#pragma unroll
  for (int k = 0; k < K_; ++k) {
    const int d  = 1 << (k >> 3);
    const int ci = min(max(i + OI[k & 7] * d, 0), H_ - 1);
    const int cj = min(max(j + OJ[k & 7] * d, 0), W_ - 1);
    float t = 0.f;
#pragma unroll
    for (int c = 0; c < CI_; ++c) {
      float v  = img[c * H_ * W_ + ci * W_ + cj];
      float dd = fabsf(v - ctr[c]) * inv[c];
      t += dd * dd;
    }
    araw[k] = -t * (1.f / CI_);
  }

  float m = araw[0];
#pragma unroll
  for (int k = 1; k < K_; ++k) m = fmaxf(m, araw[k]);
  float sum = 0.f;
#pragma unroll
  for (int k = 0; k < K_; ++k) { float e = __expf(araw[k] - m); araw[k] = e; sum += e; }
  const float rs = 1.f / sum;

  _Float16* ap = aff + ((size_t)(b * H_ + i) * K_) * W_ + j;
#pragma unroll
  for (int k = 0; k < K_; ++k) ap[k * W_] = (_Float16)(araw[k] * rs + ps.v[k]);
}

// ---------------------------------------------------------------------------
// Pad masks into edge-replicated 144x144 fp16 planes. One h4 slot per thread.
// ---------------------------------------------------------------------------
__global__ void pad_kernel(const float* __restrict__ src, _Float16* __restrict__ dst,
                           int total4) {
  int idx = blockIdx.x * blockDim.x + threadIdx.x;
  if (idx >= total4) return;
  int q  = idx % (PW_ / 4);
  int t  = idx / (PW_ / 4);
  int pi = t % PH_;
  int p  = t / PH_;
  int i = min(max(pi - PAD_, 0), H_ - 1);
  const float* srow = src + (size_t)p * (H_ * W_) + i * W_;
  h4 o;
#pragma unroll
  for (int e = 0; e < 4; ++e) {
    int j = min(max(q * 4 + e - PAD_, 0), W_ - 1);
    o[e] = (_Float16)srow[j];
  }
  *reinterpret_cast<h4*>(dst + (size_t)p * (PH_ * PW_) + pi * PW_ + q * 4) = o;
}

// ---------------------------------------------------------------------------
// iter_kernel tap macros. Thread owns 4 px of one row, 3 channels. PM = (row
// i-4, col j0), PP = (row i+4, col j0), offsets in HALF units (PW_=144). All
// compile-time immediates; all locals named scalars (nothing address-taken).
// ---------------------------------------------------------------------------

// horizontal taps, all 4 dilations, one channel (center row = PM + 4*PW_)
#define HCH(PM, ACC) do {                                                      \
    f4 m2 = ldh(PM, 4 * PW_ - 8), m1 = ldh(PM, 4 * PW_ - 4);                   \
    f4 c0 = ldh(PM, 4 * PW_),     c1 = ldh(PM, 4 * PW_ + 4);                   \
    f4 c2 = ldh(PM, 4 * PW_ + 8);                                              \
    ACC += h1m * shw<3>(m1, c0) + h1p * shw<1>(c0, c1);                        \
    ACC += h2m * shw<2>(m1, c0) + h2p * shw<2>(c0, c1);                        \
    ACC += h4m * m1 + h4p * c1;                                                \
    ACC += h8m * m2 + h8p * c2;                                                \
  } while (0)

// vertical+diagonal taps, shifted dilation D in {1,2}, SM = 4-D
#define VCHS(D, SM, PM, PP, ACC) do {                                          \
    f4 ua = ldh(PM, (4 - D) * PW_ - 4), ub = ldh(PM, (4 - D) * PW_);           \
    f4 uc = ldh(PM, (4 - D) * PW_ + 4);                                        \
    ACC += A0 * shw<SM>(ua, ub) + A1 * ub + A2 * shw<D>(ub, uc);               \
    f4 da = ldh(PP, (D - 4) * PW_ - 4), db = ldh(PP, (D - 4) * PW_);           \
    f4 dc = ldh(PP, (D - 4) * PW_ + 4);                                        \
    ACC += A5 * shw<SM>(da, db) + A6 * db + A7 * shw<D>(db, dc);               \
  } while (0)

// vertical+diagonal taps, aligned dilation 4
#define VCH4(PM, PP, ACC) do {                                                 \
    f4 ua = ldh(PM, -4), ub = ldh(PM, 0), uc = ldh(PM, 4);                     \
    ACC += A0 * ua + A1 * ub + A2 * uc;                                        \
    f4 da = ldh(PP, -4), db = ldh(PP, 0), dc = ldh(PP, 4);                     \
    ACC += A5 * da + A6 * db + A7 * dc;                                        \
  } while (0)

// vertical+diagonal taps, aligned dilation 8 (rows i-8 / i+8)
#define VCH8(PM, PP, ACC) do {                                                 \
    f4 ua = ldh(PM, -4 * PW_ - 8), ub = ldh(PM, -4 * PW_);                     \
    f4 uc = ldh(PM, -4 * PW_ + 8);                                             \
    ACC += A0 * ua + A1 * ub + A2 * uc;                                        \
    f4 da = ldh(PP, 4 * PW_ - 8), db = ldh(PP, 4 * PW_);                       \
    f4 dc = ldh(PP, 4 * PW_ + 8);                                              \
    ACC += A5 * da + A6 * db + A7 * dc;                                        \
  } while (0)

// per-dilation vertical aff fragment loads (6 f4 regs, fp16 source, NT)
#define AFFV(AB)                                                               \
    f4 A0 = ldh_nt(AB, 0),      A1 = ldh_nt(AB, W_),     A2 = ldh_nt(AB, 2 * W_); \
    f4 A5 = ldh_nt(AB, 5 * W_), A6 = ldh_nt(AB, 6 * W_), A7 = ldh_nt(AB, 7 * W_);

// ---------------------------------------------------------------------------
// Propagation step. Block 128 thr = 4 rows x 32 col-quads (4 px/thread),
// 3 channels. Grid 1792, XCD-pinned: b = bid & 7. fp16 planes + fp16 aff
// (aff loads non-temporal: streaming, keep L1 for mask rows), f32 accum.
// PADOUT=1 -> fp16 padded dst (NT stores); PADOUT=0 -> f32 d_out (NT stores).
// ---------------------------------------------------------------------------
template <int PADOUT>
__global__ __launch_bounds__(128, 3) void iter_kernel(const _Float16* __restrict__ src,
                                                      const _Float16* __restrict__ aff,
                                                      void* __restrict__ dstv) {
  const int bid  = blockIdx.x;
  const int b    = bid & 7;
  const int t    = bid >> 3;
  const int grp  = t % 7;
  const int tile = t / 7;

  const int tid = threadIdx.x;
  const int qx  = tid & 31;
  const int j0  = qx * 4;
  const int i   = tile * 4 + (tid >> 5);
  const int c0  = grp * NC_;

  constexpr int CHP = PH_ * PW_;
  const _Float16* base = src + (size_t)(b * CM_ + c0) * CHP + (i + PAD_) * PW_ + (j0 + PAD_);
  const _Float16* p0m = base           - 4 * PW_;
  const _Float16* p0p = base           + 4 * PW_;
  const _Float16* p1m = base +     CHP - 4 * PW_;
  const _Float16* p1p = base +     CHP + 4 * PW_;
  const _Float16* p2m = base + 2 * CHP - 4 * PW_;
  const _Float16* p2p = base + 2 * CHP + 4 * PW_;

  const _Float16* ab0 = aff + ((size_t)(b * H_ + i) * K_) * W_ + j0;
  const _Float16* ab1 = ab0 +  8 * W_;
  const _Float16* ab2 = ab0 + 16 * W_;
  const _Float16* ab3 = ab0 + 24 * W_;

  f4 acc0 = (f4){0.f, 0.f, 0.f, 0.f};
  f4 acc1 = (f4){0.f, 0.f, 0.f, 0.f};
  f4 acc2 = (f4){0.f, 0.f, 0.f, 0.f};

  // ---- horizontal pass: 8 aff regs (NT) + 5 center-row loads per channel
  {
    f4 h1m = ldh_nt(ab0, 3 * W_), h1p = ldh_nt(ab0, 4 * W_);
    f4 h2m = ldh_nt(ab1, 3 * W_), h2p = ldh_nt(ab1, 4 * W_);
    f4 h4m = ldh_nt(ab2, 3 * W_), h4p = ldh_nt(ab2, 4 * W_);
    f4 h8m = ldh_nt(ab3, 3 * W_), h8p = ldh_nt(ab3, 4 * W_);
    HCH(p0m, acc0);
    HCH(p1m, acc1);
    HCH(p2m, acc2);
  }
  // ---- vertical/diagonal passes, one dilation at a time
  {
    AFFV(ab0);
    VCHS(1, 3, p0m, p0p, acc0);
    VCHS(1, 3, p1m, p1p, acc1);
    VCHS(1, 3, p2m, p2p, acc2);
  }
  {
    AFFV(ab1);
    VCHS(2, 2, p0m, p0p, acc0);
    VCHS(2, 2, p1m, p1p, acc1);
    VCHS(2, 2, p2m, p2p, acc2);
  }
  {
    AFFV(ab2);
    VCH4(p0m, p0p, acc0);
    VCH4(p1m, p1p, acc1);
    VCH4(p2m, p2p, acc2);
  }
  {
    AFFV(ab3);
    VCH8(p0m, p0p, acc0);
    VCH8(p1m, p1p, acc1);
    VCH8(p2m, p2p, acc2);
  }

  // ---- epilogue (non-temporal stores: dst not re-read this iteration)
  if (PADOUT) {
    _Float16* d0 = (_Float16*)dstv + (size_t)(b * CM_ + c0) * CHP;
    _Float16* d1 = d0 + CHP;
    _Float16* d2 = d0 + 2 * CHP;
    h4 o0 = __builtin_convertvector(acc0, h4);
    h4 o1 = __builtin_convertvector(acc1, h4);
    h4 o2 = __builtin_convertvector(acc2, h4);
    const int pr = i + PAD_;
    const int r0 = (i == 0)      ? 0         : pr;
    const int r1 = (i == H_ - 1) ? (PH_ - 1) : pr;
    for (int r = r0; r <= r1; ++r) {
      _Float16* row0 = d0 + r * PW_;
      _Float16* row1 = d1 + r * PW_;
      _Float16* row2 = d2 + r * PW_;
      __builtin_nontemporal_store(o0, reinterpret_cast<h4*>(row0 + PAD_ + j0));
      __builtin_nontemporal_store(o1, reinterpret_cast<h4*>(row1 + PAD_ + j0));
      __builtin_nontemporal_store(o2, reinterpret_cast<h4*>(row2 + PAD_ + j0));
      if (qx == 0) {
        h4 s0 = (h4){o0.x, o0.x, o0.x, o0.x};
        h4 s1 = (h4){o1.x, o1.x, o1.x, o1.x};
        h4 s2 = (h4){o2.x, o2.x, o2.x, o2.x};
        __builtin_nontemporal_store(s0, reinterpret_cast<h4*>(row0));
        __builtin_nontemporal_store(s0, reinterpret_cast<h4*>(row0 + 4));
        __builtin_nontemporal_store(s1, reinterpret_cast<h4*>(row1));
        __builtin_nontemporal_store(s1, reinterpret_cast<h4*>(row1 + 4));
        __builtin_nontemporal_store(s2, reinterpret_cast<h4*>(row2));
        __builtin_nontemporal_store(s2, reinterpret_cast<h4*>(row2 + 4));
      }
      if (qx == 31) {
        h4 s0 = (h4){o0.w, o0.w, o0.w, o0.w};
        h4 s1 = (h4){o1.w, o1.w, o1.w, o1.w};
        h4 s2 = (h4){o2.w, o2.w, o2.w, o2.w};
        __builtin_nontemporal_store(s0, reinterpret_cast<h4*>(row0 + PW_ - 8));
        __builtin_nontemporal_store(s0, reinterpret_cast<h4*>(row0 + PW_ - 4));
        __builtin_nontemporal_store(s1, reinterpret_cast<h4*>(row1 + PW_ - 8));
        __builtin_nontemporal_store(s1, reinterpret_cast<h4*>(row1 + PW_ - 4));
        __builtin_nontemporal_store(s2, reinterpret_cast<h4*>(row2 + PW_ - 8));
        __builtin_nontemporal_store(s2, reinterpret_cast<h4*>(row2 + PW_ - 4));
      }
    }
  } else {
    float* dc = (float*)dstv + (size_t)(b * CM_ + c0) * (H_ * W_) + (size_t)i * W_ + j0;
    __builtin_nontemporal_store(acc0, reinterpret_cast<f4*>(dc));
    __builtin_nontemporal_store(acc1, reinterpret_cast<f4*>(dc + (H_ * W_)));
    __builtin_nontemporal_store(acc2, reinterpret_cast<f4*>(dc + 2 * (H_ * W_)));
  }
}

// ---------------------------------------------------------------------------
extern "C" void kernel_launch(void* const* d_in, const int* in_sizes, int n_in,
                              void* d_out, int out_size, void* d_ws, size_t ws_size,
                              hipStream_t stream) {
  const float* imgs  = (const float*)d_in[0];
  const float* masks = (const float*)d_in[1];
  float* out = (float*)d_out;

  char* ws = (char*)d_ws;
  const size_t affBytes = (size_t)B_ * K_ * H_ * W_ * sizeof(_Float16);     // 8.4 MB
  const size_t padBytes = (size_t)B_ * CM_ * PH_ * PW_ * sizeof(_Float16);  // 7.0 MB
  _Float16* aff = (_Float16*)ws;
  _Float16* P0  = (_Float16*)(ws + affBytes);
  _Float16* P1  = (_Float16*)(ws + affBytes + padBytes);

  PosSoft ps;
  {
    const double pv[8] = {1.4142135623730951, 1.0, 1.4142135623730951, 1.0,
                          1.0, 1.4142135623730951, 1.0, 1.4142135623730951};
    double pos[K_];
    for (int di = 0; di < 4; ++di) {
      double d = (double)(1 << di);
      for (int o = 0; o < 8; ++o) pos[di * 8 + o] = pv[o] * d;
    }
    double mean = 0; for (int k = 0; k < K_; ++k) mean += pos[k]; mean /= K_;
    double var = 0;  for (int k = 0; k < K_; ++k) { double dd = pos[k] - mean; var += dd * dd; }
    var /= (K_ - 1);
    double sd = sqrt(var);
    double pa[K_]; double m = -1e300;
    for (int k = 0; k < K_; ++k) {
      double r = pos[k] / ((sd + 1e-8) * 0.3);
      pa[k] = -(r * r);
      if (pa[k] > m) m = pa[k];
    }
    double es = 0; for (int k = 0; k < K_; ++k) { pa[k] = exp(pa[k] - m); es += pa[k]; }
    for (int k = 0; k < K_; ++k) ps.v[k] = (float)(0.01 * pa[k] / es);
  }

  aff_kernel<<<dim3(H_, B_), 128, 0, stream>>>(imgs, aff, ps);

  const int total4 = B_ * CM_ * PH_ * (PW_ / 4);
  pad_kernel<<<(total4 + 255) / 256, 256, 0, stream>>>(masks, P0, total4);

  const int nblk = B_ * 7 * (H_ / 4);   // 1792, XCD-pinned decode in kernel
  _Float16* s = P0;
  _Float16* d = P1;
  for (int it = 0; it < 9; ++it) {
    iter_kernel<1><<<nblk, 128, 0, stream>>>(s, aff, (void*)d);
    _Float16* tm = s; s = d; d = tm;
  }
  iter_kernel<0><<<nblk, 128, 0, stream>>>(s, aff, (void*)out);
}

// Round 9
// 150.376 us; speedup vs baseline: 4.2486x; 1.3655x over previous
//
#include <hip/hip_runtime.h>
#include <cmath>

#define B_   8
#define CI_  3
#define CM_  21
#define H_   128
#define W_   128
#define K_   32
#define PAD_ 8
#define PW_  144
#define PH_  144
#define NC_  3   // mask channels per block in iter kernel (21 = 7 groups of 3)

typedef float f4 __attribute__((ext_vector_type(4)));
typedef _Float16 h4 __attribute__((ext_vector_type(4)));
typedef _Float16 h8v __attribute__((ext_vector_type(8)));

struct PosSoft { float v[K_]; };

// shifted window: elements [S .. S+3] of concat(A,B); pure register selection.
template<int S>
__device__ __forceinline__ f4 shw(f4 A, f4 B) {
  if constexpr (S == 0) return A;
  else if constexpr (S == 1) return (f4){A.y, A.z, A.w, B.x};
  else if constexpr (S == 2) return (f4){A.z, A.w, B.x, B.y};
  else                       return (f4){A.w, B.x, B.y, B.z};
}

// aligned h4 global load (8 B, full-line coalesced) + widen to f4
__device__ __forceinline__ f4 ldh(const _Float16* p, int off) {
  return __builtin_convertvector(*reinterpret_cast<const h4*>(p + off), f4);
}

// ---------------------------------------------------------------------------
// Phase A: per-pixel affinity (softmax over K=32) + constant position term.
// Output layout: aff[b][i][k][j]  (k-major per row, j contiguous), fp16.
// ---------------------------------------------------------------------------
__global__ __launch_bounds__(128) void aff_kernel(const float* __restrict__ imgs,
                                                  _Float16* __restrict__ aff,
                                                  PosSoft ps) {
  constexpr int OI[8] = {-1,-1,-1, 0, 0, 1, 1, 1};
  constexpr int OJ[8] = {-1, 0, 1,-1, 1,-1, 0, 1};
  const int j = threadIdx.x;
  const int i = blockIdx.x;
  const int b = blockIdx.y;
  const float* img = imgs + (size_t)b * CI_ * H_ * W_;

  float ctr[CI_];
#pragma unroll
  for (int c = 0; c < CI_; ++c) ctr[c] = img[c * H_ * W_ + i * W_ + j];

  float s[CI_] = {0.f, 0.f, 0.f}, s2[CI_] = {0.f, 0.f, 0.f};
#pragma unroll
  for (int k = 0; k < K_; ++k) {
    const int d  = 1 << (k >> 3);
    const int ci = min(max(i + OI[k & 7] * d, 0), H_ - 1);
    const int cj = min(max(j + OJ[k & 7] * d, 0), W_ - 1);
#pragma unroll
    for (int c = 0; c < CI_; ++c) {
      float v = img[c * H_ * W_ + ci * W_ + cj];
      s[c] += v; s2[c] += v * v;
    }
  }

  float inv[CI_];
#pragma unroll
  for (int c = 0; c < CI_; ++c) {
    float mean = s[c] * (1.f / K_);
    float var  = (s2[c] - (float)K_ * mean * mean) * (1.f / (K_ - 1));
    var = fmaxf(var, 0.f);
    inv[c] = 1.f / ((sqrtf(var) + 1e-8f) * 0.3f);
  }

  float araw[K_];
#pragma unroll
  for (int k = 0; k < K_; ++k) {
    const int d  = 1 << (k >> 3);
    const int ci = min(max(i + OI[k & 7] * d, 0), H_ - 1);
    const int cj = min(max(j + OJ[k & 7] * d, 0), W_ - 1);
    float t = 0.f;
#pragma unroll
    for (int c = 0; c < CI_; ++c) {
      float v  = img[c * H_ * W_ + ci * W_ + cj];
      float dd = fabsf(v - ctr[c]) * inv[c];
      t += dd * dd;
    }
    araw[k] = -t * (1.f / CI_);
  }

  float m = araw[0];
#pragma unroll
  for (int k = 1; k < K_; ++k) m = fmaxf(m, araw[k]);
  float sum = 0.f;
#pragma unroll
  for (int k = 0; k < K_; ++k) { float e = __expf(araw[k] - m); araw[k] = e; sum += e; }
  const float rs = 1.f / sum;

  _Float16* ap = aff + ((size_t)(b * H_ + i) * K_) * W_ + j;
#pragma unroll
  for (int k = 0; k < K_; ++k) ap[k * W_] = (_Float16)(araw[k] * rs + ps.v[k]);
}

// ---------------------------------------------------------------------------
// Pad masks into edge-replicated 144x144 fp16 planes. One h4 slot per thread.
// ---------------------------------------------------------------------------
__global__ void pad_kernel(const float* __restrict__ src, _Float16* __restrict__ dst,
                           int total4) {
  int idx = blockIdx.x * blockDim.x + threadIdx.x;
  if (idx >= total4) return;
  int q  = idx % (PW_ / 4);
  int t  = idx / (PW_ / 4);
  int pi = t % PH_;
  int p  = t / PH_;
  int i = min(max(pi - PAD_, 0), H_ - 1);
  const float* srow = src + (size_t)p * (H_ * W_) + i * W_;
  h4 o;
#pragma unroll
  for (int e = 0; e < 4; ++e) {
    int j = min(max(q * 4 + e - PAD_, 0), W_ - 1);
    o[e] = (_Float16)srow[j];
  }
  *reinterpret_cast<h4*>(dst + (size_t)p * (PH_ * PW_) + pi * PW_ + q * 4) = o;
}

// ---------------------------------------------------------------------------
// iter_kernel tap macros, LDS edition. Per block: rows i0-8..i0+11 (20) x 144
// cols x 3 channels staged in sm[] (fp16, 17.3 KB). Tap reads are ds_read_b64
// with compile-time-folded offsets. lb = tr*144 + j0 (runtime part). All
// locals named scalars; LDS indices compile-time except lb.
// ---------------------------------------------------------------------------
#define LX(C, DR, CO) (lb + ((C) * 2880 + ((DR) + 8) * 144 + ((CO) + 8)))
#define LDS4(IDX) __builtin_convertvector(*reinterpret_cast<const h4*>(&sm[(IDX)]), f4)

// horizontal taps, all 4 dilations, one channel (center row dr=0)
#define HCH(C, ACC) do {                                                       \
    f4 m2 = LDS4(LX(C, 0, -8)), m1 = LDS4(LX(C, 0, -4));                       \
    f4 c0 = LDS4(LX(C, 0, 0)),  c1 = LDS4(LX(C, 0, 4));                        \
    f4 c2 = LDS4(LX(C, 0, 8));                                                 \
    ACC += h1m * shw<3>(m1, c0) + h1p * shw<1>(c0, c1);                        \
    ACC += h2m * shw<2>(m1, c0) + h2p * shw<2>(c0, c1);                        \
    ACC += h4m * m1 + h4p * c1;                                                \
    ACC += h8m * m2 + h8p * c2;                                                \
  } while (0)

// vertical+diagonal taps, shifted dilation D in {1,2}, SM = 4-D
#define VCHS(D, SM, C, ACC) do {                                               \
    f4 ua = LDS4(LX(C, -(D), -4)), ub = LDS4(LX(C, -(D), 0));                  \
    f4 uc = LDS4(LX(C, -(D), 4));                                              \
    ACC += A0 * shw<SM>(ua, ub) + A1 * ub + A2 * shw<D>(ub, uc);               \
    f4 da = LDS4(LX(C, (D), -4)), db = LDS4(LX(C, (D), 0));                    \
    f4 dc = LDS4(LX(C, (D), 4));                                               \
    ACC += A5 * shw<SM>(da, db) + A6 * db + A7 * shw<D>(db, dc);               \
  } while (0)

// vertical+diagonal taps, aligned dilation 4
#define VCH4(C, ACC) do {                                                      \
    f4 ua = LDS4(LX(C, -4, -4)), ub = LDS4(LX(C, -4, 0)), uc = LDS4(LX(C, -4, 4)); \
    ACC += A0 * ua + A1 * ub + A2 * uc;                                        \
    f4 da = LDS4(LX(C, 4, -4)), db = LDS4(LX(C, 4, 0)), dc = LDS4(LX(C, 4, 4)); \
    ACC += A5 * da + A6 * db + A7 * dc;                                        \
  } while (0)

// vertical+diagonal taps, aligned dilation 8
#define VCH8(C, ACC) do {                                                      \
    f4 ua = LDS4(LX(C, -8, -8)), ub = LDS4(LX(C, -8, 0)), uc = LDS4(LX(C, -8, 8)); \
    ACC += A0 * ua + A1 * ub + A2 * uc;                                        \
    f4 da = LDS4(LX(C, 8, -8)), db = LDS4(LX(C, 8, 0)), dc = LDS4(LX(C, 8, 8)); \
    ACC += A5 * da + A6 * db + A7 * dc;                                        \
  } while (0)

// per-dilation vertical aff fragment loads (6 f4 regs, fp16 source, cached)
#define AFFV(AB)                                                               \
    f4 A0 = ldh(AB, 0),      A1 = ldh(AB, W_),     A2 = ldh(AB, 2 * W_);       \
    f4 A5 = ldh(AB, 5 * W_), A6 = ldh(AB, 6 * W_), A7 = ldh(AB, 7 * W_);

// ---------------------------------------------------------------------------
// Propagation step. Block 128 thr = 4 rows x 32 col-quads (4 px/thread),
// 3 channels. Grid 1792, XCD-pinned: b = bid & 7. fp16 planes + fp16 aff,
// f32 accumulation. Mask taps served from LDS; aff streamed from L1/L2.
// ---------------------------------------------------------------------------
template <int PADOUT>
__global__ __launch_bounds__(128, 3) void iter_kernel(const _Float16* __restrict__ src,
                                                      const _Float16* __restrict__ aff,
                                                      void* __restrict__ dstv) {
  __shared__ _Float16 sm[NC_ * 20 * PW_];   // 3 ch x 20 rows x 144 cols = 17280 B

  const int bid  = blockIdx.x;
  const int b    = bid & 7;
  const int t    = bid >> 3;
  const int grp  = t % 7;
  const int tile = t / 7;

  const int tid = threadIdx.x;
  const int qx  = tid & 31;
  const int j0  = qx * 4;
  const int tr  = tid >> 5;          // 0..3
  const int i   = tile * 4 + tr;
  const int i0  = tile * 4;
  const int c0  = grp * NC_;

  constexpr int CHP = PH_ * PW_;

  // ---- stage: padded rows [i0 .. i0+19] (image rows i0-8..i0+11), 3 ch.
  // 16B chunks: 360 per channel (20*144/8), 1080 total; contiguous + aligned.
  {
    const _Float16* pl = src + (size_t)(b * CM_ + c0) * CHP + (size_t)i0 * PW_;
    for (int s = tid; s < 1080; s += 128) {
      int c = s / 360;
      int r = s - c * 360;
      h8v v = *reinterpret_cast<const h8v*>(pl + (size_t)c * CHP + r * 8);
      *reinterpret_cast<h8v*>(&sm[c * 2880 + r * 8]) = v;
    }
  }
  __syncthreads();

  const int lb = tr * PW_ + j0;      // runtime part of LDS tap index

  const _Float16* ab0 = aff + ((size_t)(b * H_ + i) * K_) * W_ + j0;
  const _Float16* ab1 = ab0 +  8 * W_;
  const _Float16* ab2 = ab0 + 16 * W_;
  const _Float16* ab3 = ab0 + 24 * W_;

  f4 acc0 = (f4){0.f, 0.f, 0.f, 0.f};
  f4 acc1 = (f4){0.f, 0.f, 0.f, 0.f};
  f4 acc2 = (f4){0.f, 0.f, 0.f, 0.f};

  // ---- horizontal pass: 8 aff regs + 5 center-row LDS reads per channel
  {
    f4 h1m = ldh(ab0, 3 * W_), h1p = ldh(ab0, 4 * W_);
    f4 h2m = ldh(ab1, 3 * W_), h2p = ldh(ab1, 4 * W_);
    f4 h4m = ldh(ab2, 3 * W_), h4p = ldh(ab2, 4 * W_);
    f4 h8m = ldh(ab3, 3 * W_), h8p = ldh(ab3, 4 * W_);
    HCH(0, acc0);
    HCH(1, acc1);
    HCH(2, acc2);
  }
  // ---- vertical/diagonal passes, one dilation at a time
  {
    AFFV(ab0);
    VCHS(1, 3, 0, acc0);
    VCHS(1, 3, 1, acc1);
    VCHS(1, 3, 2, acc2);
  }
  {
    AFFV(ab1);
    VCHS(2, 2, 0, acc0);
    VCHS(2, 2, 1, acc1);
    VCHS(2, 2, 2, acc2);
  }
  {
    AFFV(ab2);
    VCH4(0, acc0);
    VCH4(1, acc1);
    VCH4(2, acc2);
  }
  {
    AFFV(ab3);
    VCH8(0, acc0);
    VCH8(1, acc1);
    VCH8(2, acc2);
  }

  // ---- epilogue (plain cached stores; dst is next iteration's src)
  if (PADOUT) {
    _Float16* d0 = (_Float16*)dstv + (size_t)(b * CM_ + c0) * CHP;
    _Float16* d1 = d0 + CHP;
    _Float16* d2 = d0 + 2 * CHP;
    h4 o0 = __builtin_convertvector(acc0, h4);
    h4 o1 = __builtin_convertvector(acc1, h4);
    h4 o2 = __builtin_convertvector(acc2, h4);
    const int pr = i + PAD_;
    const int r0 = (i == 0)      ? 0         : pr;
    const int r1 = (i == H_ - 1) ? (PH_ - 1) : pr;
    for (int r = r0; r <= r1; ++r) {
      _Float16* row0 = d0 + r * PW_;
      _Float16* row1 = d1 + r * PW_;
      _Float16* row2 = d2 + r * PW_;
      *reinterpret_cast<h4*>(row0 + PAD_ + j0) = o0;
      *reinterpret_cast<h4*>(row1 + PAD_ + j0) = o1;
      *reinterpret_cast<h4*>(row2 + PAD_ + j0) = o2;
      if (qx == 0) {
        h4 s0 = (h4){o0.x, o0.x, o0.x, o0.x};
        h4 s1 = (h4){o1.x, o1.x, o1.x, o1.x};
        h4 s2 = (h4){o2.x, o2.x, o2.x, o2.x};
        *reinterpret_cast<h4*>(row0) = s0; *reinterpret_cast<h4*>(row0 + 4) = s0;
        *reinterpret_cast<h4*>(row1) = s1; *reinterpret_cast<h4*>(row1 + 4) = s1;
        *reinterpret_cast<h4*>(row2) = s2; *reinterpret_cast<h4*>(row2 + 4) = s2;
      }
      if (qx == 31) {
        h4 s0 = (h4){o0.w, o0.w, o0.w, o0.w};
        h4 s1 = (h4){o1.w, o1.w, o1.w, o1.w};
        h4 s2 = (h4){o2.w, o2.w, o2.w, o2.w};
        *reinterpret_cast<h4*>(row0 + PW_ - 8) = s0; *reinterpret_cast<h4*>(row0 + PW_ - 4) = s0;
        *reinterpret_cast<h4*>(row1 + PW_ - 8) = s1; *reinterpret_cast<h4*>(row1 + PW_ - 4) = s1;
        *reinterpret_cast<h4*>(row2 + PW_ - 8) = s2; *reinterpret_cast<h4*>(row2 + PW_ - 4) = s2;
      }
    }
  } else {
    float* dc = (float*)dstv + (size_t)(b * CM_ + c0) * (H_ * W_) + (size_t)i * W_ + j0;
    *reinterpret_cast<f4*>(dc)                 = acc0;
    *reinterpret_cast<f4*>(dc + (H_ * W_))     = acc1;
    *reinterpret_cast<f4*>(dc + 2 * (H_ * W_)) = acc2;
  }
}

// ---------------------------------------------------------------------------
extern "C" void kernel_launch(void* const* d_in, const int* in_sizes, int n_in,
                              void* d_out, int out_size, void* d_ws, size_t ws_size,
                              hipStream_t stream) {
  const float* imgs  = (const float*)d_in[0];
  const float* masks = (const float*)d_in[1];
  float* out = (float*)d_out;

  char* ws = (char*)d_ws;
  const size_t affBytes = (size_t)B_ * K_ * H_ * W_ * sizeof(_Float16);     // 8.4 MB
  const size_t padBytes = (size_t)B_ * CM_ * PH_ * PW_ * sizeof(_Float16);  // 7.0 MB
  _Float16* aff = (_Float16*)ws;
  _Float16* P0  = (_Float16*)(ws + affBytes);
  _Float16* P1  = (_Float16*)(ws + affBytes + padBytes);

  PosSoft ps;
  {
    const double pv[8] = {1.4142135623730951, 1.0, 1.4142135623730951, 1.0,
                          1.0, 1.4142135623730951, 1.0, 1.4142135623730951};
    double pos[K_];
    for (int di = 0; di < 4; ++di) {
      double d = (double)(1 << di);
      for (int o = 0; o < 8; ++o) pos[di * 8 + o] = pv[o] * d;
    }
    double mean = 0; for (int k = 0; k < K_; ++k) mean += pos[k]; mean /= K_;
    double var = 0;  for (int k = 0; k < K_; ++k) { double dd = pos[k] - mean; var += dd * dd; }
    var /= (K_ - 1);
    double sd = sqrt(var);
    double pa[K_]; double m = -1e300;
    for (int k = 0; k < K_; ++k) {
      double r = pos[k] / ((sd + 1e-8) * 0.3);
      pa[k] = -(r * r);
      if (pa[k] > m) m = pa[k];
    }
    double es = 0; for (int k = 0; k < K_; ++k) { pa[k] = exp(pa[k] - m); es += pa[k]; }
    for (int k = 0; k < K_; ++k) ps.v[k] = (float)(0.01 * pa[k] / es);
  }

  aff_kernel<<<dim3(H_, B_), 128, 0, stream>>>(imgs, aff, ps);

  const int total4 = B_ * CM_ * PH_ * (PW_ / 4);
  pad_kernel<<<(total4 + 255) / 256, 256, 0, stream>>>(masks, P0, total4);

  const int nblk = B_ * 7 * (H_ / 4);   // 1792, XCD-pinned decode in kernel
  _Float16* s = P0;
  _Float16* d = P1;
  for (int it = 0; it < 9; ++it) {
    iter_kernel<1><<<nblk, 128, 0, stream>>>(s, aff, (void*)d);
    _Float16* tm = s; s = d; d = tm;
  }
  iter_kernel<0><<<nblk, 128, 0, stream>>>(s, aff, (void*)out);
}

// Round 10
// 132.190 us; speedup vs baseline: 4.8331x; 1.1376x over previous
//
#include <hip/hip_runtime.h>
#include <cmath>

#define B_   8
#define CI_  3
#define CM_  21
#define H_   128
#define W_   128
#define K_   32
#define PAD_ 8
#define PW_  144
#define PH_  144
#define NC_  3   // mask channels per block in iter kernel (21 = 7 groups of 3)

typedef float f4 __attribute__((ext_vector_type(4)));
typedef _Float16 h4 __attribute__((ext_vector_type(4)));
typedef _Float16 h8v __attribute__((ext_vector_type(8)));

struct PosSoft { float v[K_]; };

// shifted fp16 window: elements [S .. S+3] of concat(A,B); half-select perm.
template<int S>
__device__ __forceinline__ h4 shwh(h4 A, h4 B) {
  return __builtin_shufflevector(A, B, S, S + 1, S + 2, S + 3);
}

// raw h4 global load (8 B, full-line coalesced)
__device__ __forceinline__ h4 lda(const _Float16* p, int off) {
  return *reinterpret_cast<const h4*>(p + off);
}

// ---------------------------------------------------------------------------
// Phase A: per-pixel affinity (softmax over K=32) + constant position term.
// Output layout: aff[b][i][k][j]  (k-major per row, j contiguous), fp16.
// ---------------------------------------------------------------------------
__global__ __launch_bounds__(128) void aff_kernel(const float* __restrict__ imgs,
                                                  _Float16* __restrict__ aff,
                                                  PosSoft ps) {
  constexpr int OI[8] = {-1,-1,-1, 0, 0, 1, 1, 1};
  constexpr int OJ[8] = {-1, 0, 1,-1, 1,-1, 0, 1};
  const int j = threadIdx.x;
  const int i = blockIdx.x;
  const int b = blockIdx.y;
  const float* img = imgs + (size_t)b * CI_ * H_ * W_;

  float ctr[CI_];
#pragma unroll
  for (int c = 0; c < CI_; ++c) ctr[c] = img[c * H_ * W_ + i * W_ + j];

  float s[CI_] = {0.f, 0.f, 0.f}, s2[CI_] = {0.f, 0.f, 0.f};
#pragma unroll
  for (int k = 0; k < K_; ++k) {
    const int d  = 1 << (k >> 3);
    const int ci = min(max(i + OI[k & 7] * d, 0), H_ - 1);
    const int cj = min(max(j + OJ[k & 7] * d, 0), W_ - 1);
#pragma unroll
    for (int c = 0; c < CI_; ++c) {
      float v = img[c * H_ * W_ + ci * W_ + cj];
      s[c] += v; s2[c] += v * v;
    }
  }

  float inv[CI_];
#pragma unroll
  for (int c = 0; c < CI_; ++c) {
    float mean = s[c] * (1.f / K_);
    float var  = (s2[c] - (float)K_ * mean * mean) * (1.f / (K_ - 1));
    var = fmaxf(var, 0.f);
    inv[c] = 1.f / ((sqrtf(var) + 1e-8f) * 0.3f);
  }

  float araw[K_];
#pragma unroll
  for (int k = 0; k < K_; ++k) {
    const int d  = 1 << (k >> 3);
    const int ci = min(max(i + OI[k & 7] * d, 0), H_ - 1);
    const int cj = min(max(j + OJ[k & 7] * d, 0), W_ - 1);
    float t = 0.f;
#pragma unroll
    for (int c = 0; c < CI_; ++c) {
      float v  = img[c * H_ * W_ + ci * W_ + cj];
      float dd = fabsf(v - ctr[c]) * inv[c];
      t += dd * dd;
    }
    araw[k] = -t * (1.f / CI_);
  }

  float m = araw[0];
#pragma unroll
  for (int k = 1; k < K_; ++k) m = fmaxf(m, araw[k]);
  float sum = 0.f;
#pragma unroll
  for (int k = 0; k < K_; ++k) { float e = __expf(araw[k] - m); araw[k] = e; sum += e; }
  const float rs = 1.f / sum;

  _Float16* ap = aff + ((size_t)(b * H_ + i) * K_) * W_ + j;
#pragma unroll
  for (int k = 0; k < K_; ++k) ap[k * W_] = (_Float16)(araw[k] * rs + ps.v[k]);
}

// ---------------------------------------------------------------------------
// Pad masks into edge-replicated 144x144 fp16 planes. One h4 slot per thread.
// ---------------------------------------------------------------------------
__global__ void pad_kernel(const float* __restrict__ src, _Float16* __restrict__ dst,
                           int total4) {
  int idx = blockIdx.x * blockDim.x + threadIdx.x;
  if (idx >= total4) return;
  int q  = idx % (PW_ / 4);
  int t  = idx / (PW_ / 4);
  int pi = t % PH_;
  int p  = t / PH_;
  int i = min(max(pi - PAD_, 0), H_ - 1);
  const float* srow = src + (size_t)p * (H_ * W_) + i * W_;
  h4 o;
#pragma unroll
  for (int e = 0; e < 4; ++e) {
    int j = min(max(q * 4 + e - PAD_, 0), W_ - 1);
    o[e] = (_Float16)srow[j];
  }
  *reinterpret_cast<h4*>(dst + (size_t)p * (PH_ * PW_) + pi * PW_ + q * 4) = o;
}

// ---------------------------------------------------------------------------
// iter_kernel tap macros, fp16-packed LDS edition. sm[] holds rows i0-8..
// i0+11 (20) x 144 cols x 3 channels, fp16. Taps are ds_read_b64 (h4) at
// compile-time-folded offsets; math is v_pk_fma_f16 with h4 accumulators.
// Aff fragments a00..a37 are prefetched named registers (k = dil*8 + slot;
// slots 0,1,2 = up-row, 3,4 = horiz -, +, 5,6,7 = down-row).
// ---------------------------------------------------------------------------
#define LX(C, DR, CO) (lb + ((C) * 2880 + ((DR) + 8) * 144 + ((CO) + 8)))
#define LDSH(IDX) (*reinterpret_cast<const h4*>(&sm[(IDX)]))

// horizontal taps, all 4 dilations, one channel (center row dr=0)
#define HCH(C, ACC) do {                                                       \
    h4 m2 = LDSH(LX(C, 0, -8)), m1 = LDSH(LX(C, 0, -4));                       \
    h4 c0 = LDSH(LX(C, 0, 0)),  c1 = LDSH(LX(C, 0, 4));                        \
    h4 c2 = LDSH(LX(C, 0, 8));                                                 \
    ACC += a03 * shwh<3>(m1, c0) + a04 * shwh<1>(c0, c1);                      \
    ACC += a13 * shwh<2>(m1, c0) + a14 * shwh<2>(c0, c1);                      \
    ACC += a23 * m1 + a24 * c1;                                                \
    ACC += a33 * m2 + a34 * c2;                                                \
  } while (0)

// vertical+diagonal taps, shifted dilation D in {1,2}, SM = 4-D
#define VCHS(D, SM, A0, A1, A2, A5, A6, A7, C, ACC) do {                       \
    h4 ua = LDSH(LX(C, -(D), -4)), ub = LDSH(LX(C, -(D), 0));                  \
    h4 uc = LDSH(LX(C, -(D), 4));                                              \
    ACC += A0 * shwh<SM>(ua, ub) + A1 * ub + A2 * shwh<D>(ub, uc);             \
    h4 da = LDSH(LX(C, (D), -4)), db = LDSH(LX(C, (D), 0));                    \
    h4 dc = LDSH(LX(C, (D), 4));                                               \
    ACC += A5 * shwh<SM>(da, db) + A6 * db + A7 * shwh<D>(db, dc);             \
  } while (0)

// vertical+diagonal taps, aligned dilation 4
#define VCH4(A0, A1, A2, A5, A6, A7, C, ACC) do {                              \
    h4 ua = LDSH(LX(C, -4, -4)), ub = LDSH(LX(C, -4, 0)), uc = LDSH(LX(C, -4, 4)); \
    ACC += A0 * ua + A1 * ub + A2 * uc;                                        \
    h4 da = LDSH(LX(C, 4, -4)), db = LDSH(LX(C, 4, 0)), dc = LDSH(LX(C, 4, 4)); \
    ACC += A5 * da + A6 * db + A7 * dc;                                        \
  } while (0)

// vertical+diagonal taps, aligned dilation 8
#define VCH8(A0, A1, A2, A5, A6, A7, C, ACC) do {                              \
    h4 ua = LDSH(LX(C, -8, -8)), ub = LDSH(LX(C, -8, 0)), uc = LDSH(LX(C, -8, 8)); \
    ACC += A0 * ua + A1 * ub + A2 * uc;                                        \
    h4 da = LDSH(LX(C, 8, -8)), db = LDSH(LX(C, 8, 0)), dc = LDSH(LX(C, 8, 8)); \
    ACC += A5 * da + A6 * db + A7 * dc;                                        \
  } while (0)

// ---------------------------------------------------------------------------
// Propagation step. Block 128 thr = 4 rows x 32 col-quads (4 px/thread),
// 3 channels. Grid 1792, XCD-pinned: b = bid & 7. fp16 planes + fp16 aff,
// fp16 packed accumulation. Aff prefetched pre-staging; mask taps from LDS.
// ---------------------------------------------------------------------------
template <int PADOUT>
__global__ __launch_bounds__(128, 3) void iter_kernel(const _Float16* __restrict__ src,
                                                      const _Float16* __restrict__ aff,
                                                      void* __restrict__ dstv) {
  __shared__ _Float16 sm[NC_ * 20 * PW_];   // 3 ch x 20 rows x 144 cols = 17280 B

  const int bid  = blockIdx.x;
  const int b    = bid & 7;
  const int t    = bid >> 3;
  const int grp  = t % 7;
  const int tile = t / 7;

  const int tid = threadIdx.x;
  const int qx  = tid & 31;
  const int j0  = qx * 4;
  const int tr  = tid >> 5;          // 0..3
  const int i   = tile * 4 + tr;
  const int i0  = tile * 4;
  const int c0  = grp * NC_;

  constexpr int CHP = PH_ * PW_;

  // ---- aff prefetch: 32 named h4 regs, issued before staging loads so they
  // fly under the staging latency + barrier. k = dil*8 + slot.
  const _Float16* ab = aff + ((size_t)(b * H_ + i) * K_) * W_ + j0;
  h4 a00 = lda(ab,  0 * W_), a01 = lda(ab,  1 * W_), a02 = lda(ab,  2 * W_),
     a03 = lda(ab,  3 * W_), a04 = lda(ab,  4 * W_), a05 = lda(ab,  5 * W_),
     a06 = lda(ab,  6 * W_), a07 = lda(ab,  7 * W_);
  h4 a10 = lda(ab,  8 * W_), a11 = lda(ab,  9 * W_), a12 = lda(ab, 10 * W_),
     a13 = lda(ab, 11 * W_), a14 = lda(ab, 12 * W_), a15 = lda(ab, 13 * W_),
     a16 = lda(ab, 14 * W_), a17 = lda(ab, 15 * W_);
  h4 a20 = lda(ab, 16 * W_), a21 = lda(ab, 17 * W_), a22 = lda(ab, 18 * W_),
     a23 = lda(ab, 19 * W_), a24 = lda(ab, 20 * W_), a25 = lda(ab, 21 * W_),
     a26 = lda(ab, 22 * W_), a27 = lda(ab, 23 * W_);
  h4 a30 = lda(ab, 24 * W_), a31 = lda(ab, 25 * W_), a32 = lda(ab, 26 * W_),
     a33 = lda(ab, 27 * W_), a34 = lda(ab, 28 * W_), a35 = lda(ab, 29 * W_),
     a36 = lda(ab, 30 * W_), a37 = lda(ab, 31 * W_);

  // ---- stage: padded rows [i0 .. i0+19] (image rows i0-8..i0+11), 3 ch.
  // 16B chunks: 360 per channel (20*144/8), 1080 total; contiguous + aligned.
  {
    const _Float16* pl = src + (size_t)(b * CM_ + c0) * CHP + (size_t)i0 * PW_;
    for (int s = tid; s < 1080; s += 128) {
      int c = s / 360;
      int r = s - c * 360;
      h8v v = *reinterpret_cast<const h8v*>(pl + (size_t)c * CHP + r * 8);
      *reinterpret_cast<h8v*>(&sm[c * 2880 + r * 8]) = v;
    }
  }
  __syncthreads();

  const int lb = tr * PW_ + j0;      // runtime part of LDS tap index

  h4 acc0 = (h4){0, 0, 0, 0};
  h4 acc1 = (h4){0, 0, 0, 0};
  h4 acc2 = (h4){0, 0, 0, 0};

  // ---- horizontal pass (all dilations) then vertical per dilation
  HCH(0, acc0); HCH(1, acc1); HCH(2, acc2);

  VCHS(1, 3, a00, a01, a02, a05, a06, a07, 0, acc0);
  VCHS(1, 3, a00, a01, a02, a05, a06, a07, 1, acc1);
  VCHS(1, 3, a00, a01, a02, a05, a06, a07, 2, acc2);

  VCHS(2, 2, a10, a11, a12, a15, a16, a17, 0, acc0);
  VCHS(2, 2, a10, a11, a12, a15, a16, a17, 1, acc1);
  VCHS(2, 2, a10, a11, a12, a15, a16, a17, 2, acc2);

  VCH4(a20, a21, a22, a25, a26, a27, 0, acc0);
  VCH4(a20, a21, a22, a25, a26, a27, 1, acc1);
  VCH4(a20, a21, a22, a25, a26, a27, 2, acc2);

  VCH8(a30, a31, a32, a35, a36, a37, 0, acc0);
  VCH8(a30, a31, a32, a35, a36, a37, 1, acc1);
  VCH8(a30, a31, a32, a35, a36, a37, 2, acc2);

  // ---- epilogue
  if (PADOUT) {
    _Float16* d0 = (_Float16*)dstv + (size_t)(b * CM_ + c0) * CHP;
    _Float16* d1 = d0 + CHP;
    _Float16* d2 = d0 + 2 * CHP;
    const int pr = i + PAD_;
    const int r0 = (i == 0)      ? 0         : pr;
    const int r1 = (i == H_ - 1) ? (PH_ - 1) : pr;
    for (int r = r0; r <= r1; ++r) {
      _Float16* row0 = d0 + r * PW_;
      _Float16* row1 = d1 + r * PW_;
      _Float16* row2 = d2 + r * PW_;
      *reinterpret_cast<h4*>(row0 + PAD_ + j0) = acc0;
      *reinterpret_cast<h4*>(row1 + PAD_ + j0) = acc1;
      *reinterpret_cast<h4*>(row2 + PAD_ + j0) = acc2;
      if (qx == 0) {
        h4 s0 = (h4){acc0.x, acc0.x, acc0.x, acc0.x};
        h4 s1 = (h4){acc1.x, acc1.x, acc1.x, acc1.x};
        h4 s2 = (h4){acc2.x, acc2.x, acc2.x, acc2.x};
        *reinterpret_cast<h4*>(row0) = s0; *reinterpret_cast<h4*>(row0 + 4) = s0;
        *reinterpret_cast<h4*>(row1) = s1; *reinterpret_cast<h4*>(row1 + 4) = s1;
        *reinterpret_cast<h4*>(row2) = s2; *reinterpret_cast<h4*>(row2 + 4) = s2;
      }
      if (qx == 31) {
        h4 s0 = (h4){acc0.w, acc0.w, acc0.w, acc0.w};
        h4 s1 = (h4){acc1.w, acc1.w, acc1.w, acc1.w};
        h4 s2 = (h4){acc2.w, acc2.w, acc2.w, acc2.w};
        *reinterpret_cast<h4*>(row0 + PW_ - 8) = s0; *reinterpret_cast<h4*>(row0 + PW_ - 4) = s0;
        *reinterpret_cast<h4*>(row1 + PW_ - 8) = s1; *reinterpret_cast<h4*>(row1 + PW_ - 4) = s1;
        *reinterpret_cast<h4*>(row2 + PW_ - 8) = s2; *reinterpret_cast<h4*>(row2 + PW_ - 4) = s2;
      }
    }
  } else {
    float* dc = (float*)dstv + (size_t)(b * CM_ + c0) * (H_ * W_) + (size_t)i * W_ + j0;
    *reinterpret_cast<f4*>(dc)                 = __builtin_convertvector(acc0, f4);
    *reinterpret_cast<f4*>(dc + (H_ * W_))     = __builtin_convertvector(acc1, f4);
    *reinterpret_cast<f4*>(dc + 2 * (H_ * W_)) = __builtin_convertvector(acc2, f4);
  }
}

// ---------------------------------------------------------------------------
extern "C" void kernel_launch(void* const* d_in, const int* in_sizes, int n_in,
                              void* d_out, int out_size, void* d_ws, size_t ws_size,
                              hipStream_t stream) {
  const float* imgs  = (const float*)d_in[0];
  const float* masks = (const float*)d_in[1];
  float* out = (float*)d_out;

  char* ws = (char*)d_ws;
  const size_t affBytes = (size_t)B_ * K_ * H_ * W_ * sizeof(_Float16);     // 8.4 MB
  const size_t padBytes = (size_t)B_ * CM_ * PH_ * PW_ * sizeof(_Float16);  // 7.0 MB
  _Float16* aff = (_Float16*)ws;
  _Float16* P0  = (_Float16*)(ws + affBytes);
  _Float16* P1  = (_Float16*)(ws + affBytes + padBytes);

  PosSoft ps;
  {
    const double pv[8] = {1.4142135623730951, 1.0, 1.4142135623730951, 1.0,
                          1.0, 1.4142135623730951, 1.0, 1.4142135623730951};
    double pos[K_];
    for (int di = 0; di < 4; ++di) {
      double d = (double)(1 << di);
      for (int o = 0; o < 8; ++o) pos[di * 8 + o] = pv[o] * d;
    }
    double mean = 0; for (int k = 0; k < K_; ++k) mean += pos[k]; mean /= K_;
    double var = 0;  for (int k = 0; k < K_; ++k) { double dd = pos[k] - mean; var += dd * dd; }
    var /= (K_ - 1);
    double sd = sqrt(var);
    double pa[K_]; double m = -1e300;
    for (int k = 0; k < K_; ++k) {
      double r = pos[k] / ((sd + 1e-8) * 0.3);
      pa[k] = -(r * r);
      if (pa[k] > m) m = pa[k];
    }
    double es = 0; for (int k = 0; k < K_; ++k) { pa[k] = exp(pa[k] - m); es += pa[k]; }
    for (int k = 0; k < K_; ++k) ps.v[k] = (float)(0.01 * pa[k] / es);
  }

  aff_kernel<<<dim3(H_, B_), 128, 0, stream>>>(imgs, aff, ps);

  const int total4 = B_ * CM_ * PH_ * (PW_ / 4);
  pad_kernel<<<(total4 + 255) / 256, 256, 0, stream>>>(masks, P0, total4);

  const int nblk = B_ * 7 * (H_ / 4);   // 1792, XCD-pinned decode in kernel
  _Float16* s = P0;
  _Float16* d = P1;
  for (int it = 0; it < 9; ++it) {
    iter_kernel<1><<<nblk, 128, 0, stream>>>(s, aff, (void*)d);
    _Float16* tm = s; s = d; d = tm;
  }
  iter_kernel<0><<<nblk, 128, 0, stream>>>(s, aff, (void*)out);
}